// Round 2
// baseline (292.728 us; speedup 1.0000x reference)
//
#include <hip/hip_runtime.h>
#include <stdint.h>

#define NRAYS 2048
#define SMAX  192
#define RESG  128
#define STEPF 0.027f
#define ERTF  1e-4f
#define CAP   (NRAYS * SMAX)   // 393216

// ---------------- ray/aabb ----------------
__device__ __forceinline__ void ray_aabb(float ox, float oy, float oz,
                                         float dx, float dy, float dz,
                                         float& tn, float& tf) {
    float ix = 1.0f / ((fabsf(dx) < 1e-9f) ? 1e-9f : dx);
    float iy = 1.0f / ((fabsf(dy) < 1e-9f) ? 1e-9f : dy);
    float iz = 1.0f / ((fabsf(dz) < 1e-9f) ? 1e-9f : dz);
    float t0x = (-1.5f - ox) * ix, t1x = (1.5f - ox) * ix;
    float t0y = (-1.5f - oy) * iy, t1y = (1.5f - oy) * iy;
    float t0z = (-1.5f - oz) * iz, t1z = (1.5f - oz) * iz;
    float tnx = fminf(t0x, t1x), tfx = fmaxf(t0x, t1x);
    float tny = fminf(t0y, t1y), tfy = fmaxf(t0y, t1y);
    float tnz = fminf(t0z, t1z), tfz = fmaxf(t0z, t1z);
    tn = fmaxf(fmaxf(fmaxf(tnx, tny), tnz), 0.0f);
    tf = fminf(fminf(tfx, tfy), tfz);
}

__global__ void k_init(int* cnt) { if (threadIdx.x == 0) *cnt = 0; }

// ---------------- kernel 1: march + compact actives, zero dense ----------------
__global__ __launch_bounds__(256) void k_march(
        const float* __restrict__ ro, const float* __restrict__ rd,
        const int* __restrict__ occ, int* __restrict__ cnt,
        int2* __restrict__ ids, float4* __restrict__ pos, float4* __restrict__ dense) {
    int idx = blockIdx.x * 256 + threadIdx.x;
    if (idx >= CAP) return;
    int r = idx / SMAX;
    int s = idx - r * SMAX;
    float ox = ro[r*3+0], oy = ro[r*3+1], oz = ro[r*3+2];
    float dx = rd[r*3+0], dy = rd[r*3+1], dz = rd[r*3+2];
    float tn, tf;
    ray_aabb(ox, oy, oz, dx, dy, dz, tn, tf);
    float t_mid = (tn + STEPF * (float)s) + 0.5f * STEPF;
    bool inside = (t_mid < tf) && (tf > tn);
    float px = ox + dx * t_mid;
    float py = oy + dy * t_mid;
    float pz = oz + dz * t_mid;
    bool act = false;
    if (inside) {
        int gx = (int)((px + 1.5f) / 3.0f * 128.0f);
        int gy = (int)((py + 1.5f) / 3.0f * 128.0f);
        int gz = (int)((pz + 1.5f) / 3.0f * 128.0f);
        gx = min(max(gx, 0), RESG - 1);
        gy = min(max(gy, 0), RESG - 1);
        gz = min(max(gz, 0), RESG - 1);
        act = occ[(gx * RESG + gy) * RESG + gz] != 0;   // occ_grid is int32 (bool -> int)
    }
    dense[idx] = make_float4(0.0f, 0.0f, 0.0f, 0.0f);
    unsigned long long mb = __ballot(act);
    int lane = threadIdx.x & 63;
    int nact = __popcll(mb);
    if (nact) {
        int base = 0;
        if (lane == 0) base = atomicAdd(cnt, nact);
        base = __shfl(base, 0);
        if (act) {
            int off = base + __popcll(mb & ((1ull << lane) - 1ull));
            ids[off] = make_int2(r, s);
            pos[off] = make_float4(px, py, pz, t_mid);
        }
    }
}

// ---------------- kernel 2: batched MLP over active samples ----------------
__device__ __forceinline__ void fma8(float acc[8], float a, const float4 wa, const float4 wb) {
    acc[0] = fmaf(a, wa.x, acc[0]); acc[1] = fmaf(a, wa.y, acc[1]);
    acc[2] = fmaf(a, wa.z, acc[2]); acc[3] = fmaf(a, wa.w, acc[3]);
    acc[4] = fmaf(a, wb.x, acc[4]); acc[5] = fmaf(a, wb.y, acc[5]);
    acc[6] = fmaf(a, wb.z, acc[6]); acc[7] = fmaf(a, wb.w, acc[7]);
}

#define BT 512

__global__ __launch_bounds__(512) void k_mlp(
        const float* __restrict__ W0, const float* __restrict__ W1,
        const float* __restrict__ wsig, const float* __restrict__ W2,
        const float* __restrict__ wrgb, const float* __restrict__ vd,
        const int* __restrict__ cnt, const int2* __restrict__ ids,
        const float4* __restrict__ pos, float4* __restrict__ dense) {
    __shared__ float sPE[64][68];                 // 63 used; stride 68 -> <=2-way banks
    __shared__ float sPD[64][36];                 // 27 used
    __shared__ float sH [64][132];                // 128 used
    __shared__ __align__(16) float sW[80 * 128];  // per-layer weight staging (40 KB)
    __shared__ float sV[128];                     // w_sigma
    __shared__ float sR[384];                     // w_rgb [128][3]
    __shared__ float4 sPos[64];
    __shared__ int2  sIds[64];

    const int tid = threadIdx.x;
    if (tid < 128) sV[tid] = wsig[tid];
    if (tid >= 128 && tid < 512) sR[tid - 128] = wrgb[tid - 128];

    const int total  = *cnt;
    const int ntiles = (total + 63) >> 6;
    const int ty = tid >> 4;        // 0..31
    const int tx = tid & 15;        // 0..15
    const int m0 = ty * 2;          // 2 samples / thread
    const int j0 = tx * 8;          // 8 outputs / thread

    for (int t = blockIdx.x; t < ntiles; t += gridDim.x) {
        const int base = t << 6;
        __syncthreads();   // protect sIds/sPos/sW from previous tile
        if (tid < 64) {
            int gi = base + tid;
            if (gi < total) { sIds[tid] = ids[gi]; sPos[tid] = pos[gi]; }
            else            { sIds[tid] = make_int2(0, 0); sPos[tid] = make_float4(0,0,0,0); }
        }
        __syncthreads();

        // ---- positional encodings (+ stage W0 into sW) ----
        {
            int m = tid >> 3, p = tid & 7;
            float4 P = sPos[m];
            if (p == 0) { sPE[m][0] = P.x; sPE[m][1] = P.y; sPE[m][2] = P.z; }
            for (int l = p; l < 10; l += 8) {
                float f = (float)(1 << l);
                int o = 3 + 6 * l;
                sPE[m][o+0] = __sinf(P.x * f); sPE[m][o+1] = __sinf(P.y * f); sPE[m][o+2] = __sinf(P.z * f);
                sPE[m][o+3] = __cosf(P.x * f); sPE[m][o+4] = __cosf(P.y * f); sPE[m][o+5] = __cosf(P.z * f);
            }
            int ray = sIds[m].x;
            const float* dv = vd + 3 * ray;
            float ddx = dv[0], ddy = dv[1], ddz = dv[2];
            if (p == 4) { sPD[m][0] = ddx; sPD[m][1] = ddy; sPD[m][2] = ddz; }
            if (p < 4) {
                float f = (float)(1 << p);
                int o = 3 + 6 * p;
                sPD[m][o+0] = __sinf(ddx * f); sPD[m][o+1] = __sinf(ddy * f); sPD[m][o+2] = __sinf(ddz * f);
                sPD[m][o+3] = __cosf(ddx * f); sPD[m][o+4] = __cosf(ddy * f); sPD[m][o+5] = __cosf(ddz * f);
            }
            const float4* src = (const float4*)W0;
            float4* dst = (float4*)sW;
            for (int i = tid; i < 2016; i += BT) dst[i] = src[i];  // 63*128 floats
        }
        __syncthreads();

        // ---- layer 0: h = relu(peP @ W0) ----
        {
            float acc[2][8];
            #pragma unroll
            for (int mm = 0; mm < 2; ++mm)
                #pragma unroll
                for (int jj = 0; jj < 8; ++jj) acc[mm][jj] = 0.0f;
            #pragma unroll 4
            for (int k = 0; k < 63; ++k) {
                const float4 wa = *(const float4*)&sW[k * 128 + j0];
                const float4 wb = *(const float4*)&sW[k * 128 + j0 + 4];
                fma8(acc[0], sPE[m0 + 0][k], wa, wb);
                fma8(acc[1], sPE[m0 + 1][k], wa, wb);
            }
            #pragma unroll
            for (int mm = 0; mm < 2; ++mm) {   // sH rows are wave-private
                *(float4*)&sH[m0 + mm][j0]     = make_float4(fmaxf(acc[mm][0],0.f), fmaxf(acc[mm][1],0.f), fmaxf(acc[mm][2],0.f), fmaxf(acc[mm][3],0.f));
                *(float4*)&sH[m0 + mm][j0 + 4] = make_float4(fmaxf(acc[mm][4],0.f), fmaxf(acc[mm][5],0.f), fmaxf(acc[mm][6],0.f), fmaxf(acc[mm][7],0.f));
            }
        }

        // ---- layer 1: h = relu(h @ W1); sigma = h @ w_sigma ----
        float sig[2];
        {
            float acc[2][8];
            #pragma unroll
            for (int mm = 0; mm < 2; ++mm)
                #pragma unroll
                for (int jj = 0; jj < 8; ++jj) acc[mm][jj] = 0.0f;
            for (int part = 0; part < 2; ++part) {
                __syncthreads();   // everyone done with previous sW contents
                {
                    const float4* src = (const float4*)(W1 + part * 64 * 128);
                    float4* dst = (float4*)sW;
                    for (int i = tid; i < 2048; i += BT) dst[i] = src[i];
                }
                __syncthreads();
                const int kbase = part * 64;
                #pragma unroll 4
                for (int k = 0; k < 64; ++k) {
                    const float4 wa = *(const float4*)&sW[k * 128 + j0];
                    const float4 wb = *(const float4*)&sW[k * 128 + j0 + 4];
                    fma8(acc[0], sH[m0 + 0][kbase + k], wa, wb);
                    fma8(acc[1], sH[m0 + 1][kbase + k], wa, wb);
                }
            }
            #pragma unroll
            for (int mm = 0; mm < 2; ++mm) {
                float h[8];
                float sp = 0.0f;
                #pragma unroll
                for (int jj = 0; jj < 8; ++jj) {
                    h[jj] = fmaxf(acc[mm][jj], 0.0f);
                    sp = fmaf(h[jj], sV[j0 + jj], sp);
                }
                #pragma unroll
                for (int off = 1; off < 16; off <<= 1) sp += __shfl_xor(sp, off, 16);
                sig[mm] = sp;
                *(float4*)&sH[m0 + mm][j0]     = make_float4(h[0], h[1], h[2], h[3]);
                *(float4*)&sH[m0 + mm][j0 + 4] = make_float4(h[4], h[5], h[6], h[7]);
            }
        }

        // ---- layer 2: h2 = relu(concat(h, peD) @ W2); rgb = sigmoid(h2 @ w_rgb) ----
        {
            float acc[2][8];
            #pragma unroll
            for (int mm = 0; mm < 2; ++mm)
                #pragma unroll
                for (int jj = 0; jj < 8; ++jj) acc[mm][jj] = 0.0f;
            // part 0: rows 0..79 (all from sH)
            __syncthreads();
            {
                const float4* src = (const float4*)W2;
                float4* dst = (float4*)sW;
                for (int i = tid; i < 2560; i += BT) dst[i] = src[i];
            }
            __syncthreads();
            #pragma unroll 4
            for (int k = 0; k < 80; ++k) {
                const float4 wa = *(const float4*)&sW[k * 128 + j0];
                const float4 wb = *(const float4*)&sW[k * 128 + j0 + 4];
                fma8(acc[0], sH[m0 + 0][k], wa, wb);
                fma8(acc[1], sH[m0 + 1][k], wa, wb);
            }
            // part 1: rows 80..154 (80..127 from sH, 128..154 from sPD)
            __syncthreads();
            {
                const float4* src = (const float4*)(W2 + 80 * 128);
                float4* dst = (float4*)sW;
                for (int i = tid; i < 2400; i += BT) dst[i] = src[i];
            }
            __syncthreads();
            #pragma unroll 4
            for (int k = 80; k < 128; ++k) {
                const float4 wa = *(const float4*)&sW[(k - 80) * 128 + j0];
                const float4 wb = *(const float4*)&sW[(k - 80) * 128 + j0 + 4];
                fma8(acc[0], sH[m0 + 0][k], wa, wb);
                fma8(acc[1], sH[m0 + 1][k], wa, wb);
            }
            #pragma unroll
            for (int k = 128; k < 155; ++k) {
                const float4 wa = *(const float4*)&sW[(k - 80) * 128 + j0];
                const float4 wb = *(const float4*)&sW[(k - 80) * 128 + j0 + 4];
                fma8(acc[0], sPD[m0 + 0][k - 128], wa, wb);
                fma8(acc[1], sPD[m0 + 1][k - 128], wa, wb);
            }
            // epilogue: rgb partials -> cross-tx reduce -> sigmoid -> scatter
            float rp0[2] = {0, 0}, rp1[2] = {0, 0}, rp2[2] = {0, 0};
            #pragma unroll
            for (int mm = 0; mm < 2; ++mm) {
                #pragma unroll
                for (int jj = 0; jj < 8; ++jj) {
                    float h2 = fmaxf(acc[mm][jj], 0.0f);
                    int j = j0 + jj;
                    rp0[mm] = fmaf(h2, sR[j * 3 + 0], rp0[mm]);
                    rp1[mm] = fmaf(h2, sR[j * 3 + 1], rp1[mm]);
                    rp2[mm] = fmaf(h2, sR[j * 3 + 2], rp2[mm]);
                }
                #pragma unroll
                for (int off = 1; off < 16; off <<= 1) {
                    rp0[mm] += __shfl_xor(rp0[mm], off, 16);
                    rp1[mm] += __shfl_xor(rp1[mm], off, 16);
                    rp2[mm] += __shfl_xor(rp2[mm], off, 16);
                }
            }
            if (tx == 0) {
                #pragma unroll
                for (int mm = 0; mm < 2; ++mm) {
                    int gi = base + m0 + mm;
                    if (gi < total) {
                        int2 id = sIds[m0 + mm];
                        float alpha = 1.0f - __expf(-fmaxf(sig[mm], 0.0f) * STEPF);
                        float r0 = 1.0f / (1.0f + __expf(-rp0[mm]));
                        float r1 = 1.0f / (1.0f + __expf(-rp1[mm]));
                        float r2 = 1.0f / (1.0f + __expf(-rp2[mm]));
                        dense[id.x * SMAX + id.y] = make_float4(r0, r1, r2, alpha);
                    }
                }
            }
        }
    }
}

// ---------------- kernel 3: per-ray compositing (1 wave / ray) ----------------
__global__ __launch_bounds__(256) void k_render(
        const float* __restrict__ ro, const float* __restrict__ rd,
        const float4* __restrict__ dense, float* __restrict__ out) {
    int r = blockIdx.x * 4 + (threadIdx.x >> 6);
    int lane = threadIdx.x & 63;
    float ox = ro[r*3+0], oy = ro[r*3+1], oz = ro[r*3+2];
    float dx = rd[r*3+0], dy = rd[r*3+1], dz = rd[r*3+2];
    float tn, tf;
    ray_aabb(ox, oy, oz, dx, dy, dz, tn, tf);
    float T_run = 1.0f;
    float cr = 0.f, cg = 0.f, cb = 0.f, opa = 0.f, dep = 0.f;
    #pragma unroll
    for (int c = 0; c < 3; ++c) {
        int s = c * 64 + lane;
        float4 f = dense[r * SMAX + s];
        float alpha = f.w;
        float g = 1.0f - alpha + 1e-10f;
        float p = g;
        #pragma unroll
        for (int off = 1; off < 64; off <<= 1) {
            float v = __shfl_up(p, off);
            if (lane >= off) p *= v;
        }
        float pprev = __shfl_up(p, 1);
        float Texc = (lane == 0) ? T_run : T_run * pprev;
        Texc = (Texc > ERTF) ? Texc : 0.0f;
        float w = Texc * alpha;
        float tmid = (tn + STEPF * (float)s) + 0.5f * STEPF;
        cr += w * f.x; cg += w * f.y; cb += w * f.z;
        opa += w; dep += w * tmid;
        T_run *= __shfl(p, 63);
    }
    #pragma unroll
    for (int off = 32; off; off >>= 1) {
        cr  += __shfl_xor(cr, off);
        cg  += __shfl_xor(cg, off);
        cb  += __shfl_xor(cb, off);
        opa += __shfl_xor(opa, off);
        dep += __shfl_xor(dep, off);
    }
    if (lane == 0) {
        out[r * 3 + 0] = cr + (1.0f - opa);
        out[r * 3 + 1] = cg + (1.0f - opa);
        out[r * 3 + 2] = cb + (1.0f - opa);
        out[NRAYS * 3 + r] = dep;            // depth
        out[NRAYS * 4 + r] = opa;            // opacity
    }
}

extern "C" void kernel_launch(void* const* d_in, const int* in_sizes, int n_in,
                              void* d_out, int out_size, void* d_ws, size_t ws_size,
                              hipStream_t stream) {
    const float* ro   = (const float*)d_in[0];
    const float* rd   = (const float*)d_in[1];
    const int*   occ  = (const int*)d_in[2];
    const float* W0   = (const float*)d_in[3];
    const float* W1   = (const float*)d_in[4];
    const float* wsig = (const float*)d_in[5];
    const float* W2   = (const float*)d_in[6];
    const float* wrgb = (const float*)d_in[7];
    float* out = (float*)d_out;

    int*    cnt   = (int*)d_ws;
    int2*   ids   = (int2*)  ((char*)d_ws + 16);
    float4* pos   = (float4*)((char*)d_ws + 16 + (size_t)CAP * 8);
    float4* dense = (float4*)((char*)d_ws + 16 + (size_t)CAP * 8 + (size_t)CAP * 16);

    k_init  <<<1, 64, 0, stream>>>(cnt);
    k_march <<<CAP / 256, 256, 0, stream>>>(ro, rd, occ, cnt, ids, pos, dense);
    k_mlp   <<<1024, 512, 0, stream>>>(W0, W1, wsig, W2, wrgb, rd, cnt, ids, pos, dense);
    k_render<<<NRAYS / 4, 256, 0, stream>>>(ro, rd, dense, out);
}

// Round 5
// 172.857 us; speedup vs baseline: 1.6935x; 1.6935x over previous
//
#include <hip/hip_runtime.h>
#include <stdint.h>

#define NRAYS 2048
#define SMAX  192
#define RESG  128
#define STEPF 0.027f
#define ERTF  1e-4f
#define CAP   (NRAYS * SMAX)   // 393216

typedef __attribute__((ext_vector_type(8)))  short bf16x8;   // 8 bf16 = 4 VGPR
typedef __attribute__((ext_vector_type(16))) float f32x16;   // MFMA 32x32 acc

// ---- bf16 helpers (RNE) ----
__device__ __forceinline__ uint32_t f2b(float x) {
    uint32_t u = __builtin_bit_cast(uint32_t, x);
    return (u + 0x7fffu + ((u >> 16) & 1u)) >> 16;
}
__device__ __forceinline__ uint32_t bpack(float lo, float hi) {
    return f2b(lo) | (f2b(hi) << 16);
}

// ---------------- ray/aabb ----------------
__device__ __forceinline__ void ray_aabb(float ox, float oy, float oz,
                                         float dx, float dy, float dz,
                                         float& tn, float& tf) {
    float ix = 1.0f / ((fabsf(dx) < 1e-9f) ? 1e-9f : dx);
    float iy = 1.0f / ((fabsf(dy) < 1e-9f) ? 1e-9f : dy);
    float iz = 1.0f / ((fabsf(dz) < 1e-9f) ? 1e-9f : dz);
    float t0x = (-1.5f - ox) * ix, t1x = (1.5f - ox) * ix;
    float t0y = (-1.5f - oy) * iy, t1y = (1.5f - oy) * iy;
    float t0z = (-1.5f - oz) * iz, t1z = (1.5f - oz) * iz;
    float tnx = fminf(t0x, t1x), tfx = fmaxf(t0x, t1x);
    float tny = fminf(t0y, t1y), tfy = fmaxf(t0y, t1y);
    float tnz = fminf(t0z, t1z), tfz = fmaxf(t0z, t1z);
    tn = fmaxf(fmaxf(fmaxf(tnx, tny), tnz), 0.0f);
    tf = fminf(fminf(tfx, tfy), tfz);
}

__global__ void k_init(int* cnt) { if (threadIdx.x == 0) *cnt = 0; }

// ---------------- weight fragment prep ----------------
// 88 blocks x 64 threads; blockIdx = g*4 + oc.
// g: 0..3 -> W0 (K 0..63, rows>=63 zero), 4..11 -> W1, 12..21 -> W2 (rows>=155 zero)
// A-frag for mfma_32x32x16: lane holds row(out)=lane&31, k=(lane>>5)*8+e, e=0..7
__global__ void k_prep(const float* __restrict__ W0, const float* __restrict__ W1,
                       const float* __restrict__ W2, uint32_t* __restrict__ wf) {
    int b = blockIdx.x;
    int g = b >> 2, oc = b & 3;
    int lane = threadIdx.x;
    int out = oc * 32 + (lane & 31);
    const float* W; int kbase, Klim;
    if (g < 4)       { W = W0; kbase = g * 16;        Klim = 63;  }
    else if (g < 12) { W = W1; kbase = (g - 4) * 16;  Klim = 128; }
    else             { W = W2; kbase = (g - 12) * 16; Klim = 155; }
    uint32_t d[4];
    #pragma unroll
    for (int h = 0; h < 4; ++h) {
        int k0 = kbase + ((lane >> 5) << 3) + h * 2;
        float lo = (k0     < Klim) ? W[(size_t)k0 * 128 + out]       : 0.0f;
        float hi = (k0 + 1 < Klim) ? W[(size_t)(k0 + 1) * 128 + out] : 0.0f;
        d[h] = bpack(lo, hi);
    }
    ((uint4*)wf)[b * 64 + lane] = make_uint4(d[0], d[1], d[2], d[3]);
}

// ---------------- kernel 1: march + compact actives, zero dense ----------------
__global__ __launch_bounds__(256) void k_march(
        const float* __restrict__ ro, const float* __restrict__ rd,
        const int* __restrict__ occ, int* __restrict__ cnt,
        int2* __restrict__ ids, float4* __restrict__ pos, float4* __restrict__ dense) {
    int idx = blockIdx.x * 256 + threadIdx.x;
    if (idx >= CAP) return;
    int r = idx / SMAX;
    int s = idx - r * SMAX;
    float ox = ro[r*3+0], oy = ro[r*3+1], oz = ro[r*3+2];
    float dx = rd[r*3+0], dy = rd[r*3+1], dz = rd[r*3+2];
    float tn, tf;
    ray_aabb(ox, oy, oz, dx, dy, dz, tn, tf);
    float t_mid = (tn + STEPF * (float)s) + 0.5f * STEPF;
    bool inside = (t_mid < tf) && (tf > tn);
    float px = ox + dx * t_mid;
    float py = oy + dy * t_mid;
    float pz = oz + dz * t_mid;
    bool act = false;
    if (inside) {
        int gx = (int)((px + 1.5f) / 3.0f * 128.0f);
        int gy = (int)((py + 1.5f) / 3.0f * 128.0f);
        int gz = (int)((pz + 1.5f) / 3.0f * 128.0f);
        gx = min(max(gx, 0), RESG - 1);
        gy = min(max(gy, 0), RESG - 1);
        gz = min(max(gz, 0), RESG - 1);
        act = occ[(gx * RESG + gy) * RESG + gz] != 0;
    }
    dense[idx] = make_float4(0.0f, 0.0f, 0.0f, 0.0f);
    unsigned long long mb = __ballot(act);
    int lane = threadIdx.x & 63;
    int nact = __popcll(mb);
    if (nact) {
        int base = 0;
        if (lane == 0) base = atomicAdd(cnt, nact);
        base = __shfl(base, 0);
        if (act) {
            int off = base + __popcll(mb & ((1ull << lane) - 1ull));
            ids[off] = make_int2(r, s);
            pos[off] = make_float4(px, py, pz, t_mid);
        }
    }
}

// ---------------- kernel 2: MFMA MLP ----------------
// Block 512 = 8 waves = 4 out-chunks(32) x 2 sample-chunks(32). Tile = 64 samples.
// Layout invariant: activation LDS rows are [sample][col], physical byte =
//   row*rowB + (logical_col_byte ^ ((row&15)<<4)).
// D' = Wchunk(A, regs) x act(B, LDS): D col=lane&31=sample, row=out=(r&3)+8*(r>>2)+4*(lane>>5).
__global__ __launch_bounds__(512) void k_mlp(
        const uint32_t* __restrict__ wfrag, const float* __restrict__ wsig,
        const float* __restrict__ wrgb, const float* __restrict__ vd,
        const int* __restrict__ cnt, const int2* __restrict__ ids,
        const float4* __restrict__ pos, float4* __restrict__ dense) {
    __shared__ __align__(16) short actA[64 * 128];   // 16KB, rowB=256B: pe_p -> h_b
    __shared__ __align__(16) short bufB[64 * 256];   // 32KB, rowB=512B: [h_a|pe_d] -> [h2|pe_d]
    __shared__ float4 sPos[64];
    __shared__ int    sSlot[64];
    __shared__ int    sRay[64];
    __shared__ float  sV[128];
    __shared__ float  sR[384];

    const int tid  = threadIdx.x;
    const int wave = tid >> 6;
    const int lane = tid & 63;
    const int oc   = wave & 3;
    const int sc   = wave >> 2;
    const int lo5  = lane & 31;
    const int hi5  = lane >> 5;

    if (tid < 128) sV[tid] = wsig[tid];
    if (tid >= 128 && tid < 512) sR[tid - 128] = wrgb[tid - 128];

    // ---- weight fragments: held in VGPR across all tiles (22 x 4 = 88 VGPR) ----
    bf16x8 wf[22];
    {
        const uint4* src = (const uint4*)wfrag;
        #pragma unroll
        for (int g = 0; g < 22; ++g) {
            uint4 v = src[(g * 4 + oc) * 64 + lane];
            wf[g] = __builtin_bit_cast(bf16x8, v);
        }
    }

    const int total  = *cnt;
    const int ntiles = (total + 63) >> 6;
    const int mrow   = sc * 32 + lo5;           // this lane's sample (B-col)
    const int rswz   = (mrow & 15) << 4;

    for (int t = blockIdx.x; t < ntiles; t += gridDim.x) {
        const int base = t << 6;
        __syncthreads();                         // previous tile fully consumed
        if (tid < 64) {
            int gi = base + tid;
            if (gi < total) {
                int2 id = ids[gi];
                sSlot[tid] = id.x * SMAX + id.y;
                sRay[tid]  = id.x;
                sPos[tid]  = pos[gi];
            } else {
                sSlot[tid] = 0; sRay[tid] = 0;
                sPos[tid]  = make_float4(0.f, 0.f, 0.f, 0.f);
            }
        }
        __syncthreads();

        // ---- PE: pe_p -> actA cols 0..63 (col63=0); pe_d -> bufB cols 128..159 (155+=0) ----
        {
            int m = tid >> 3, p = tid & 7;
            float4 P = sPos[m];
            int swz = (m & 15) << 4;
            uint32_t dw[4];
            #pragma unroll
            for (int jp = 0; jp < 4; ++jp) {
                float v[2];
                #pragma unroll
                for (int q = 0; q < 2; ++q) {
                    int c = p * 8 + jp * 2 + q;
                    float val;
                    if (c < 3)        val = (c == 0) ? P.x : ((c == 1) ? P.y : P.z);
                    else if (c >= 63) val = 0.0f;
                    else {
                        int cc = c - 3, l = cc / 6, jj = cc - 6 * l;
                        int a3 = (jj >= 3) ? jj - 3 : jj;
                        float comp = (a3 == 0) ? P.x : ((a3 == 1) ? P.y : P.z);
                        float arg = comp * (float)(1 << l);
                        val = (jj < 3) ? __sinf(arg) : __cosf(arg);
                    }
                    v[q] = val;
                }
                dw[jp] = bpack(v[0], v[1]);
            }
            *(uint4*)((char*)actA + m * 256 + ((p * 16) ^ swz)) = make_uint4(dw[0], dw[1], dw[2], dw[3]);
            if (p < 4) {
                int ray = sRay[m];
                float Dx = vd[ray*3+0], Dy = vd[ray*3+1], Dz = vd[ray*3+2];
                #pragma unroll
                for (int jp = 0; jp < 4; ++jp) {
                    float v[2];
                    #pragma unroll
                    for (int q = 0; q < 2; ++q) {
                        int c = p * 8 + jp * 2 + q;     // 0..31
                        float val;
                        if (c < 3)        val = (c == 0) ? Dx : ((c == 1) ? Dy : Dz);
                        else if (c >= 27) val = 0.0f;
                        else {
                            int cc = c - 3, l = cc / 6, jj = cc - 6 * l;
                            int a3 = (jj >= 3) ? jj - 3 : jj;
                            float comp = (a3 == 0) ? Dx : ((a3 == 1) ? Dy : Dz);
                            float arg = comp * (float)(1 << l);
                            val = (jj < 3) ? __sinf(arg) : __cosf(arg);
                        }
                        v[q] = val;
                    }
                    dw[jp] = bpack(v[0], v[1]);
                }
                *(uint4*)((char*)bufB + m * 512 + ((256 + p * 16) ^ swz)) = make_uint4(dw[0], dw[1], dw[2], dw[3]);
            }
        }
        __syncthreads();

        // ---- L0: h_a = relu(pe_p @ W0) -> bufB cols 0..127 ----
        {
            f32x16 acc = {};
            #pragma unroll
            for (int kb = 0; kb < 4; ++kb) {
                bf16x8 bf = *(const bf16x8*)((const char*)actA + mrow * 256 + ((kb * 32 + (hi5 << 4)) ^ rswz));
                acc = __builtin_amdgcn_mfma_f32_32x32x16_bf16(wf[kb], bf, acc, 0, 0, 0);
            }
            #pragma unroll
            for (int g = 0; g < 4; ++g) {
                int outb = (oc * 32 + g * 8 + (hi5 << 2)) * 2;
                uint32_t d0 = bpack(fmaxf(acc[g*4+0], 0.f), fmaxf(acc[g*4+1], 0.f));
                uint32_t d1 = bpack(fmaxf(acc[g*4+2], 0.f), fmaxf(acc[g*4+3], 0.f));
                *(uint2*)((char*)bufB + mrow * 512 + (outb ^ rswz)) = make_uint2(d0, d1);
            }
        }
        __syncthreads();

        // ---- L1: h_b = relu(h_a @ W1) -> actA ----
        {
            f32x16 acc = {};
            #pragma unroll
            for (int kb = 0; kb < 8; ++kb) {
                bf16x8 bf = *(const bf16x8*)((const char*)bufB + mrow * 512 + ((kb * 32 + (hi5 << 4)) ^ rswz));
                acc = __builtin_amdgcn_mfma_f32_32x32x16_bf16(wf[4 + kb], bf, acc, 0, 0, 0);
            }
            #pragma unroll
            for (int g = 0; g < 4; ++g) {
                int outb = (oc * 32 + g * 8 + (hi5 << 2)) * 2;
                uint32_t d0 = bpack(fmaxf(acc[g*4+0], 0.f), fmaxf(acc[g*4+1], 0.f));
                uint32_t d1 = bpack(fmaxf(acc[g*4+2], 0.f), fmaxf(acc[g*4+3], 0.f));
                *(uint2*)((char*)actA + mrow * 256 + (outb ^ rswz)) = make_uint2(d0, d1);
            }
        }
        __syncthreads();

        // ---- L2: h2 = relu([h_b | pe_d] @ W2) -> bufB cols 0..127 ----
        {
            f32x16 acc = {};
            #pragma unroll
            for (int kb = 0; kb < 8; ++kb) {
                bf16x8 bf = *(const bf16x8*)((const char*)actA + mrow * 256 + ((kb * 32 + (hi5 << 4)) ^ rswz));
                acc = __builtin_amdgcn_mfma_f32_32x32x16_bf16(wf[12 + kb], bf, acc, 0, 0, 0);
            }
            #pragma unroll
            for (int kb = 8; kb < 10; ++kb) {
                bf16x8 bf = *(const bf16x8*)((const char*)bufB + mrow * 512 + ((kb * 32 + (hi5 << 4)) ^ rswz));
                acc = __builtin_amdgcn_mfma_f32_32x32x16_bf16(wf[12 + kb], bf, acc, 0, 0, 0);
            }
            #pragma unroll
            for (int g = 0; g < 4; ++g) {
                int outb = (oc * 32 + g * 8 + (hi5 << 2)) * 2;
                uint32_t d0 = bpack(fmaxf(acc[g*4+0], 0.f), fmaxf(acc[g*4+1], 0.f));
                uint32_t d1 = bpack(fmaxf(acc[g*4+2], 0.f), fmaxf(acc[g*4+3], 0.f));
                *(uint2*)((char*)bufB + mrow * 512 + (outb ^ rswz)) = make_uint2(d0, d1);
            }
        }
        __syncthreads();

        // ---- heads: sigma = h_b @ wsig ; rgb = sigmoid(h2 @ wrgb) ----
        {
            int m = tid >> 3, p = tid & 7;
            int swz = (m & 15) << 4;
            float sp = 0.f, r0 = 0.f, r1 = 0.f, r2 = 0.f;
            #pragma unroll
            for (int hh = 0; hh < 2; ++hh) {
                uint4 q = *(const uint4*)((const char*)actA + m * 256 + ((p * 32 + hh * 16) ^ swz));
                uint32_t w[4] = {q.x, q.y, q.z, q.w};
                #pragma unroll
                for (int e = 0; e < 4; ++e) {
                    int j = p * 16 + hh * 8 + e * 2;
                    float a0 = __builtin_bit_cast(float, w[e] << 16);
                    float a1 = __builtin_bit_cast(float, w[e] & 0xffff0000u);
                    sp = fmaf(a0, sV[j], sp);
                    sp = fmaf(a1, sV[j + 1], sp);
                }
            }
            #pragma unroll
            for (int hh = 0; hh < 2; ++hh) {
                uint4 q = *(const uint4*)((const char*)bufB + m * 512 + ((p * 32 + hh * 16) ^ swz));
                uint32_t w[4] = {q.x, q.y, q.z, q.w};
                #pragma unroll
                for (int e = 0; e < 4; ++e) {
                    int j = p * 16 + hh * 8 + e * 2;
                    float a0 = __builtin_bit_cast(float, w[e] << 16);
                    float a1 = __builtin_bit_cast(float, w[e] & 0xffff0000u);
                    r0 = fmaf(a0, sR[j*3+0], r0); r1 = fmaf(a0, sR[j*3+1], r1); r2 = fmaf(a0, sR[j*3+2], r2);
                    r0 = fmaf(a1, sR[(j+1)*3+0], r0); r1 = fmaf(a1, sR[(j+1)*3+1], r1); r2 = fmaf(a1, sR[(j+1)*3+2], r2);
                }
            }
            #pragma unroll
            for (int off = 1; off < 8; off <<= 1) {
                sp += __shfl_xor(sp, off);
                r0 += __shfl_xor(r0, off);
                r1 += __shfl_xor(r1, off);
                r2 += __shfl_xor(r2, off);
            }
            if (p == 0 && (base + m) < total) {
                float alpha = 1.0f - __expf(-fmaxf(sp, 0.0f) * STEPF);
                float c0 = 1.0f / (1.0f + __expf(-r0));
                float c1 = 1.0f / (1.0f + __expf(-r1));
                float c2 = 1.0f / (1.0f + __expf(-r2));
                dense[sSlot[m]] = make_float4(c0, c1, c2, alpha);
            }
        }
    }
}

// ---------------- kernel 3: per-ray compositing (1 wave / ray) ----------------
__global__ __launch_bounds__(256) void k_render(
        const float* __restrict__ ro, const float* __restrict__ rd,
        const float4* __restrict__ dense, float* __restrict__ out) {
    int r = blockIdx.x * 4 + (threadIdx.x >> 6);
    int lane = threadIdx.x & 63;
    float ox = ro[r*3+0], oy = ro[r*3+1], oz = ro[r*3+2];
    float dx = rd[r*3+0], dy = rd[r*3+1], dz = rd[r*3+2];
    float tn, tf;
    ray_aabb(ox, oy, oz, dx, dy, dz, tn, tf);
    float T_run = 1.0f;
    float cr = 0.f, cg = 0.f, cb = 0.f, opa = 0.f, dep = 0.f;
    #pragma unroll
    for (int c = 0; c < 3; ++c) {
        int s = c * 64 + lane;
        float4 f = dense[r * SMAX + s];
        float alpha = f.w;
        float g = 1.0f - alpha + 1e-10f;
        float p = g;
        #pragma unroll
        for (int off = 1; off < 64; off <<= 1) {
            float v = __shfl_up(p, off);
            if (lane >= off) p *= v;
        }
        float pprev = __shfl_up(p, 1);
        float Texc = (lane == 0) ? T_run : T_run * pprev;
        Texc = (Texc > ERTF) ? Texc : 0.0f;
        float w = Texc * alpha;
        float tmid = (tn + STEPF * (float)s) + 0.5f * STEPF;
        cr += w * f.x; cg += w * f.y; cb += w * f.z;
        opa += w; dep += w * tmid;
        T_run *= __shfl(p, 63);
    }
    #pragma unroll
    for (int off = 32; off; off >>= 1) {
        cr  += __shfl_xor(cr, off);
        cg  += __shfl_xor(cg, off);
        cb  += __shfl_xor(cb, off);
        opa += __shfl_xor(opa, off);
        dep += __shfl_xor(dep, off);
    }
    if (lane == 0) {
        out[r * 3 + 0] = cr + (1.0f - opa);
        out[r * 3 + 1] = cg + (1.0f - opa);
        out[r * 3 + 2] = cb + (1.0f - opa);
        out[NRAYS * 3 + r] = dep;            // depth
        out[NRAYS * 4 + r] = opa;            // opacity
    }
}

extern "C" void kernel_launch(void* const* d_in, const int* in_sizes, int n_in,
                              void* d_out, int out_size, void* d_ws, size_t ws_size,
                              hipStream_t stream) {
    const float* ro   = (const float*)d_in[0];
    const float* rd   = (const float*)d_in[1];
    const int*   occ  = (const int*)d_in[2];
    const float* W0   = (const float*)d_in[3];
    const float* W1   = (const float*)d_in[4];
    const float* wsig = (const float*)d_in[5];
    const float* W2   = (const float*)d_in[6];
    const float* wrgb = (const float*)d_in[7];
    float* out = (float*)d_out;

    int*      cnt   = (int*)d_ws;
    int2*     ids   = (int2*)   ((char*)d_ws + 16);
    float4*   pos   = (float4*) ((char*)d_ws + 16 + (size_t)CAP * 8);
    float4*   dense = (float4*) ((char*)d_ws + 16 + (size_t)CAP * 8 + (size_t)CAP * 16);
    uint32_t* wfrag = (uint32_t*)((char*)d_ws + 16 + (size_t)CAP * 40);   // 88*64*16B

    k_init  <<<1, 64, 0, stream>>>(cnt);
    k_prep  <<<88, 64, 0, stream>>>(W0, W1, W2, wfrag);
    k_march <<<CAP / 256, 256, 0, stream>>>(ro, rd, occ, cnt, ids, pos, dense);
    k_mlp   <<<1024, 512, 0, stream>>>(wfrag, wsig, wrgb, rd, cnt, ids, pos, dense);
    k_render<<<NRAYS / 4, 256, 0, stream>>>(ro, rd, dense, out);
}

// Round 6
// 119.562 us; speedup vs baseline: 2.4483x; 1.4458x over previous
//
#include <hip/hip_runtime.h>
#include <stdint.h>

#define NRAYS 2048
#define SMAX  192
#define RESG  128
#define STEPF 0.027f
#define ERTF  1e-4f
#define CAP   (NRAYS * SMAX)   // 393216

typedef __attribute__((ext_vector_type(8)))  short bf16x8;   // 8 bf16 = 4 VGPR
typedef __attribute__((ext_vector_type(16))) float f32x16;   // MFMA 32x32 acc

// ---- bf16 helpers (RNE) ----
__device__ __forceinline__ uint32_t f2b(float x) {
    uint32_t u = __builtin_bit_cast(uint32_t, x);
    return (u + 0x7fffu + ((u >> 16) & 1u)) >> 16;
}
__device__ __forceinline__ uint32_t bpack(float lo, float hi) {
    return f2b(lo) | (f2b(hi) << 16);
}

// ---------------- ray/aabb ----------------
__device__ __forceinline__ void ray_aabb(float ox, float oy, float oz,
                                         float dx, float dy, float dz,
                                         float& tn, float& tf) {
    float ix = 1.0f / ((fabsf(dx) < 1e-9f) ? 1e-9f : dx);
    float iy = 1.0f / ((fabsf(dy) < 1e-9f) ? 1e-9f : dy);
    float iz = 1.0f / ((fabsf(dz) < 1e-9f) ? 1e-9f : dz);
    float t0x = (-1.5f - ox) * ix, t1x = (1.5f - ox) * ix;
    float t0y = (-1.5f - oy) * iy, t1y = (1.5f - oy) * iy;
    float t0z = (-1.5f - oz) * iz, t1z = (1.5f - oz) * iz;
    float tnx = fminf(t0x, t1x), tfx = fmaxf(t0x, t1x);
    float tny = fminf(t0y, t1y), tfy = fmaxf(t0y, t1y);
    float tnz = fminf(t0z, t1z), tfz = fmaxf(t0z, t1z);
    tn = fmaxf(fmaxf(fmaxf(tnx, tny), tnz), 0.0f);
    tf = fminf(fminf(tfx, tfy), tfz);
}

// ---------------- weight fragment prep (unchanged) ----------------
__global__ void k_prep(const float* __restrict__ W0, const float* __restrict__ W1,
                       const float* __restrict__ W2, uint32_t* __restrict__ wf) {
    int b = blockIdx.x;
    int g = b >> 2, oc = b & 3;
    int lane = threadIdx.x;
    int out = oc * 32 + (lane & 31);
    const float* W; int kbase, Klim;
    if (g < 4)       { W = W0; kbase = g * 16;        Klim = 63;  }
    else if (g < 12) { W = W1; kbase = (g - 4) * 16;  Klim = 128; }
    else             { W = W2; kbase = (g - 12) * 16; Klim = 155; }
    uint32_t d[4];
    #pragma unroll
    for (int h = 0; h < 4; ++h) {
        int k0 = kbase + ((lane >> 5) << 3) + h * 2;
        float lo = (k0     < Klim) ? W[(size_t)k0 * 128 + out]       : 0.0f;
        float hi = (k0 + 1 < Klim) ? W[(size_t)(k0 + 1) * 128 + out] : 0.0f;
        d[h] = bpack(lo, hi);
    }
    ((uint4*)wf)[b * 64 + lane] = make_uint4(d[0], d[1], d[2], d[3]);
}

// ---------------- stage 1: per-ray occupancy masks + counts (no atomics) ----------------
__global__ __launch_bounds__(256) void k_count(
        const float* __restrict__ ro, const float* __restrict__ rd,
        const int* __restrict__ occ,
        int* __restrict__ rayCount, unsigned long long* __restrict__ masks) {
    int r = blockIdx.x * 4 + (threadIdx.x >> 6);
    int lane = threadIdx.x & 63;
    float ox = ro[r*3+0], oy = ro[r*3+1], oz = ro[r*3+2];
    float dx = rd[r*3+0], dy = rd[r*3+1], dz = rd[r*3+2];
    float tn, tf;
    ray_aabb(ox, oy, oz, dx, dy, dz, tn, tf);
    int cnt = 0;
    #pragma unroll
    for (int c = 0; c < 3; ++c) {
        int s = c * 64 + lane;
        float t_mid = (tn + STEPF * (float)s) + 0.5f * STEPF;
        bool inside = (t_mid < tf) && (tf > tn);
        bool act = false;
        if (inside) {
            float px = ox + dx * t_mid;
            float py = oy + dy * t_mid;
            float pz = oz + dz * t_mid;
            int gx = min(max((int)((px + 1.5f) / 3.0f * 128.0f), 0), RESG - 1);
            int gy = min(max((int)((py + 1.5f) / 3.0f * 128.0f), 0), RESG - 1);
            int gz = min(max((int)((pz + 1.5f) / 3.0f * 128.0f), 0), RESG - 1);
            act = occ[(gx * RESG + gy) * RESG + gz] != 0;
        }
        unsigned long long mb = __ballot(act);
        if (lane == 0) masks[r * 3 + c] = mb;
        cnt += __popcll(mb);
    }
    if (lane == 0) rayCount[r] = cnt;
}

// ---------------- stage 2: exclusive scan of 2048 ray counts ----------------
__global__ __launch_bounds__(1024) void k_scan(
        const int* __restrict__ rayCount, int* __restrict__ rayOff,
        int* __restrict__ cnt_total) {
    __shared__ int wsum[16];
    int tid = threadIdx.x;              // 0..1023, pair (2*tid, 2*tid+1)
    int a = rayCount[2 * tid], b = rayCount[2 * tid + 1];
    int s = a + b;
    int lane = tid & 63, w = tid >> 6;
    int v = s;
    #pragma unroll
    for (int off = 1; off < 64; off <<= 1) {
        int t = __shfl_up(v, off);
        if (lane >= off) v += t;
    }
    if (lane == 63) wsum[w] = v;
    __syncthreads();
    if (tid < 16) {
        int x = wsum[tid];
        #pragma unroll
        for (int off = 1; off < 16; off <<= 1) {
            int t = __shfl_up(x, off, 16);
            if (tid >= off) x += t;
        }
        wsum[tid] = x;                  // inclusive wave-sum scan
    }
    __syncthreads();
    int wbase = (w == 0) ? 0 : wsum[w - 1];
    int incl = wbase + v;               // inclusive through pair tid
    int excl = incl - s;
    rayOff[2 * tid]     = excl;
    rayOff[2 * tid + 1] = excl + a;
    if (tid == 1023) cnt_total[0] = incl;
}

// ---------------- stage 3: write compacted ids/pos (ray-sorted, deterministic) ----------------
__global__ __launch_bounds__(256) void k_fill(
        const float* __restrict__ ro, const float* __restrict__ rd,
        const int* __restrict__ rayOff, const unsigned long long* __restrict__ masks,
        int2* __restrict__ ids, float4* __restrict__ pos) {
    int r = blockIdx.x * 4 + (threadIdx.x >> 6);
    int lane = threadIdx.x & 63;
    float ox = ro[r*3+0], oy = ro[r*3+1], oz = ro[r*3+2];
    float dx = rd[r*3+0], dy = rd[r*3+1], dz = rd[r*3+2];
    float tn, tf;
    ray_aabb(ox, oy, oz, dx, dy, dz, tn, tf);
    int base = rayOff[r];
    #pragma unroll
    for (int c = 0; c < 3; ++c) {
        unsigned long long m = masks[r * 3 + c];
        if ((m >> lane) & 1ull) {
            int within = __popcll(m & ((1ull << lane) - 1ull));
            int s = c * 64 + lane;
            float t_mid = (tn + STEPF * (float)s) + 0.5f * STEPF;
            float px = ox + dx * t_mid;
            float py = oy + dy * t_mid;
            float pz = oz + dz * t_mid;
            ids[base + within] = make_int2(r, s);
            pos[base + within] = make_float4(px, py, pz, t_mid);
        }
        base += __popcll(m);
    }
}

// ---------------- kernel 2: MFMA MLP (compact coalesced output) ----------------
__global__ __launch_bounds__(512) void k_mlp(
        const uint32_t* __restrict__ wfrag, const float* __restrict__ wsig,
        const float* __restrict__ wrgb, const float* __restrict__ vd,
        const int* __restrict__ cnt, const int2* __restrict__ ids,
        const float4* __restrict__ pos, float4* __restrict__ rgba) {
    __shared__ __align__(16) short actA[64 * 128];   // 16KB, rowB=256B
    __shared__ __align__(16) short bufB[64 * 256];   // 32KB, rowB=512B
    __shared__ float4 sPos[64];
    __shared__ int    sRay[64];
    __shared__ float  sV[128];
    __shared__ float  sR[384];

    const int tid  = threadIdx.x;
    const int wave = tid >> 6;
    const int lane = tid & 63;
    const int oc   = wave & 3;
    const int sc   = wave >> 2;
    const int lo5  = lane & 31;
    const int hi5  = lane >> 5;

    if (tid < 128) sV[tid] = wsig[tid];
    if (tid >= 128 && tid < 512) sR[tid - 128] = wrgb[tid - 128];

    bf16x8 wf[22];
    {
        const uint4* src = (const uint4*)wfrag;
        #pragma unroll
        for (int g = 0; g < 22; ++g) {
            uint4 v = src[(g * 4 + oc) * 64 + lane];
            wf[g] = __builtin_bit_cast(bf16x8, v);
        }
    }

    const int total  = *cnt;
    const int ntiles = (total + 63) >> 6;
    const int mrow   = sc * 32 + lo5;
    const int rswz   = (mrow & 15) << 4;

    for (int t = blockIdx.x; t < ntiles; t += gridDim.x) {
        const int base = t << 6;
        __syncthreads();
        if (tid < 64) {
            int gi = base + tid;
            if (gi < total) { sRay[tid] = ids[gi].x; sPos[tid] = pos[gi]; }
            else            { sRay[tid] = 0; sPos[tid] = make_float4(0.f,0.f,0.f,0.f); }
        }
        __syncthreads();

        // ---- PE ----
        {
            int m = tid >> 3, p = tid & 7;
            float4 P = sPos[m];
            int swz = (m & 15) << 4;
            uint32_t dw[4];
            #pragma unroll
            for (int jp = 0; jp < 4; ++jp) {
                float v[2];
                #pragma unroll
                for (int q = 0; q < 2; ++q) {
                    int c = p * 8 + jp * 2 + q;
                    float val;
                    if (c < 3)        val = (c == 0) ? P.x : ((c == 1) ? P.y : P.z);
                    else if (c >= 63) val = 0.0f;
                    else {
                        int cc = c - 3, l = cc / 6, jj = cc - 6 * l;
                        int a3 = (jj >= 3) ? jj - 3 : jj;
                        float comp = (a3 == 0) ? P.x : ((a3 == 1) ? P.y : P.z);
                        float arg = comp * (float)(1 << l);
                        val = (jj < 3) ? __sinf(arg) : __cosf(arg);
                    }
                    v[q] = val;
                }
                dw[jp] = bpack(v[0], v[1]);
            }
            *(uint4*)((char*)actA + m * 256 + ((p * 16) ^ swz)) = make_uint4(dw[0], dw[1], dw[2], dw[3]);
            if (p < 4) {
                int ray = sRay[m];
                float Dx = vd[ray*3+0], Dy = vd[ray*3+1], Dz = vd[ray*3+2];
                #pragma unroll
                for (int jp = 0; jp < 4; ++jp) {
                    float v[2];
                    #pragma unroll
                    for (int q = 0; q < 2; ++q) {
                        int c = p * 8 + jp * 2 + q;
                        float val;
                        if (c < 3)        val = (c == 0) ? Dx : ((c == 1) ? Dy : Dz);
                        else if (c >= 27) val = 0.0f;
                        else {
                            int cc = c - 3, l = cc / 6, jj = cc - 6 * l;
                            int a3 = (jj >= 3) ? jj - 3 : jj;
                            float comp = (a3 == 0) ? Dx : ((a3 == 1) ? Dy : Dz);
                            float arg = comp * (float)(1 << l);
                            val = (jj < 3) ? __sinf(arg) : __cosf(arg);
                        }
                        v[q] = val;
                    }
                    dw[jp] = bpack(v[0], v[1]);
                }
                *(uint4*)((char*)bufB + m * 512 + ((256 + p * 16) ^ swz)) = make_uint4(dw[0], dw[1], dw[2], dw[3]);
            }
        }
        __syncthreads();

        // ---- L0 ----
        {
            f32x16 acc = {};
            #pragma unroll
            for (int kb = 0; kb < 4; ++kb) {
                bf16x8 bf = *(const bf16x8*)((const char*)actA + mrow * 256 + ((kb * 32 + (hi5 << 4)) ^ rswz));
                acc = __builtin_amdgcn_mfma_f32_32x32x16_bf16(wf[kb], bf, acc, 0, 0, 0);
            }
            #pragma unroll
            for (int g = 0; g < 4; ++g) {
                int outb = (oc * 32 + g * 8 + (hi5 << 2)) * 2;
                uint32_t d0 = bpack(fmaxf(acc[g*4+0], 0.f), fmaxf(acc[g*4+1], 0.f));
                uint32_t d1 = bpack(fmaxf(acc[g*4+2], 0.f), fmaxf(acc[g*4+3], 0.f));
                *(uint2*)((char*)bufB + mrow * 512 + (outb ^ rswz)) = make_uint2(d0, d1);
            }
        }
        __syncthreads();

        // ---- L1 ----
        {
            f32x16 acc = {};
            #pragma unroll
            for (int kb = 0; kb < 8; ++kb) {
                bf16x8 bf = *(const bf16x8*)((const char*)bufB + mrow * 512 + ((kb * 32 + (hi5 << 4)) ^ rswz));
                acc = __builtin_amdgcn_mfma_f32_32x32x16_bf16(wf[4 + kb], bf, acc, 0, 0, 0);
            }
            #pragma unroll
            for (int g = 0; g < 4; ++g) {
                int outb = (oc * 32 + g * 8 + (hi5 << 2)) * 2;
                uint32_t d0 = bpack(fmaxf(acc[g*4+0], 0.f), fmaxf(acc[g*4+1], 0.f));
                uint32_t d1 = bpack(fmaxf(acc[g*4+2], 0.f), fmaxf(acc[g*4+3], 0.f));
                *(uint2*)((char*)actA + mrow * 256 + (outb ^ rswz)) = make_uint2(d0, d1);
            }
        }
        __syncthreads();

        // ---- L2 ----
        {
            f32x16 acc = {};
            #pragma unroll
            for (int kb = 0; kb < 8; ++kb) {
                bf16x8 bf = *(const bf16x8*)((const char*)actA + mrow * 256 + ((kb * 32 + (hi5 << 4)) ^ rswz));
                acc = __builtin_amdgcn_mfma_f32_32x32x16_bf16(wf[12 + kb], bf, acc, 0, 0, 0);
            }
            #pragma unroll
            for (int kb = 8; kb < 10; ++kb) {
                bf16x8 bf = *(const bf16x8*)((const char*)bufB + mrow * 512 + ((kb * 32 + (hi5 << 4)) ^ rswz));
                acc = __builtin_amdgcn_mfma_f32_32x32x16_bf16(wf[12 + kb], bf, acc, 0, 0, 0);
            }
            #pragma unroll
            for (int g = 0; g < 4; ++g) {
                int outb = (oc * 32 + g * 8 + (hi5 << 2)) * 2;
                uint32_t d0 = bpack(fmaxf(acc[g*4+0], 0.f), fmaxf(acc[g*4+1], 0.f));
                uint32_t d1 = bpack(fmaxf(acc[g*4+2], 0.f), fmaxf(acc[g*4+3], 0.f));
                *(uint2*)((char*)bufB + mrow * 512 + (outb ^ rswz)) = make_uint2(d0, d1);
            }
        }
        __syncthreads();

        // ---- heads ----
        {
            int m = tid >> 3, p = tid & 7;
            int swz = (m & 15) << 4;
            float sp = 0.f, r0 = 0.f, r1 = 0.f, r2 = 0.f;
            #pragma unroll
            for (int hh = 0; hh < 2; ++hh) {
                uint4 q = *(const uint4*)((const char*)actA + m * 256 + ((p * 32 + hh * 16) ^ swz));
                uint32_t w[4] = {q.x, q.y, q.z, q.w};
                #pragma unroll
                for (int e = 0; e < 4; ++e) {
                    int j = p * 16 + hh * 8 + e * 2;
                    float a0 = __builtin_bit_cast(float, w[e] << 16);
                    float a1 = __builtin_bit_cast(float, w[e] & 0xffff0000u);
                    sp = fmaf(a0, sV[j], sp);
                    sp = fmaf(a1, sV[j + 1], sp);
                }
            }
            #pragma unroll
            for (int hh = 0; hh < 2; ++hh) {
                uint4 q = *(const uint4*)((const char*)bufB + m * 512 + ((p * 32 + hh * 16) ^ swz));
                uint32_t w[4] = {q.x, q.y, q.z, q.w};
                #pragma unroll
                for (int e = 0; e < 4; ++e) {
                    int j = p * 16 + hh * 8 + e * 2;
                    float a0 = __builtin_bit_cast(float, w[e] << 16);
                    float a1 = __builtin_bit_cast(float, w[e] & 0xffff0000u);
                    r0 = fmaf(a0, sR[j*3+0], r0); r1 = fmaf(a0, sR[j*3+1], r1); r2 = fmaf(a0, sR[j*3+2], r2);
                    r0 = fmaf(a1, sR[(j+1)*3+0], r0); r1 = fmaf(a1, sR[(j+1)*3+1], r1); r2 = fmaf(a1, sR[(j+1)*3+2], r2);
                }
            }
            #pragma unroll
            for (int off = 1; off < 8; off <<= 1) {
                sp += __shfl_xor(sp, off);
                r0 += __shfl_xor(r0, off);
                r1 += __shfl_xor(r1, off);
                r2 += __shfl_xor(r2, off);
            }
            if (p == 0 && (base + m) < total) {
                float alpha = 1.0f - __expf(-fmaxf(sp, 0.0f) * STEPF);
                float c0 = 1.0f / (1.0f + __expf(-r0));
                float c1 = 1.0f / (1.0f + __expf(-r1));
                float c2 = 1.0f / (1.0f + __expf(-r2));
                rgba[base + m] = make_float4(c0, c1, c2, alpha);
            }
        }
    }
}

// ---------------- kernel 3: compositing over compact per-ray ranges ----------------
__global__ __launch_bounds__(256) void k_render(
        const int* __restrict__ rayOff, const int* __restrict__ rayCount,
        const float4* __restrict__ rgba, const float* __restrict__ posw,
        float* __restrict__ out) {
    int r = blockIdx.x * 4 + (threadIdx.x >> 6);
    int lane = threadIdx.x & 63;
    int off = rayOff[r], cnt = rayCount[r];
    float T_run = 1.0f;
    float cr = 0.f, cg = 0.f, cb = 0.f, opa = 0.f, dep = 0.f;
    for (int j = 0; j < cnt; j += 64) {
        int idx = j + lane;
        float4 f = make_float4(0.f, 0.f, 0.f, 0.f);
        float tmid = 0.f;
        if (idx < cnt) {
            f = rgba[off + idx];
            tmid = posw[(size_t)(off + idx) * 4 + 3];
        }
        float p = (1.0f - f.w) + 1e-10f;
        #pragma unroll
        for (int o = 1; o < 64; o <<= 1) {
            float v = __shfl_up(p, o);
            if (lane >= o) p *= v;
        }
        float pprev = __shfl_up(p, 1);
        float Texc = (lane == 0) ? T_run : T_run * pprev;
        Texc = (Texc > ERTF) ? Texc : 0.0f;
        float w = Texc * f.w;
        cr += w * f.x; cg += w * f.y; cb += w * f.z;
        opa += w; dep += w * tmid;
        T_run *= __shfl(p, 63);
        if (T_run <= ERTF) break;      // exact: all later exclusive-T <= ERT -> zero weight
    }
    #pragma unroll
    for (int o = 32; o; o >>= 1) {
        cr  += __shfl_xor(cr, o);
        cg  += __shfl_xor(cg, o);
        cb  += __shfl_xor(cb, o);
        opa += __shfl_xor(opa, o);
        dep += __shfl_xor(dep, o);
    }
    if (lane == 0) {
        out[r * 3 + 0] = cr + (1.0f - opa);
        out[r * 3 + 1] = cg + (1.0f - opa);
        out[r * 3 + 2] = cb + (1.0f - opa);
        out[NRAYS * 3 + r] = dep;            // depth
        out[NRAYS * 4 + r] = opa;            // opacity
    }
}

extern "C" void kernel_launch(void* const* d_in, const int* in_sizes, int n_in,
                              void* d_out, int out_size, void* d_ws, size_t ws_size,
                              hipStream_t stream) {
    const float* ro   = (const float*)d_in[0];
    const float* rd   = (const float*)d_in[1];
    const int*   occ  = (const int*)d_in[2];
    const float* W0   = (const float*)d_in[3];
    const float* W1   = (const float*)d_in[4];
    const float* wsig = (const float*)d_in[5];
    const float* W2   = (const float*)d_in[6];
    const float* wrgb = (const float*)d_in[7];
    float* out = (float*)d_out;

    char* ws = (char*)d_ws;
    int*                cnt_total = (int*)ws;                              // 16 B
    int*                rayCount  = (int*)(ws + 16);                       // 8 KB
    int*                rayOff    = (int*)(ws + 8208);                     // 8 KB
    unsigned long long* masks     = (unsigned long long*)(ws + 16400);     // 48 KB
    int2*               ids       = (int2*)(ws + 65552);                   // CAP*8
    float4*             pos       = (float4*)(ws + 65552 + (size_t)CAP * 8);
    float4*             rgba      = (float4*)(ws + 65552 + (size_t)CAP * 24);
    uint32_t*           wfrag     = (uint32_t*)(ws + 65552 + (size_t)CAP * 40);  // 88*64*16B

    k_prep  <<<88, 64, 0, stream>>>(W0, W1, W2, wfrag);
    k_count <<<NRAYS / 4, 256, 0, stream>>>(ro, rd, occ, rayCount, masks);
    k_scan  <<<1, 1024, 0, stream>>>(rayCount, rayOff, cnt_total);
    k_fill  <<<NRAYS / 4, 256, 0, stream>>>(ro, rd, rayOff, masks, ids, pos);
    k_mlp   <<<1024, 512, 0, stream>>>(wfrag, wsig, wrgb, rd, cnt_total, ids, pos, rgba);
    k_render<<<NRAYS / 4, 256, 0, stream>>>(rayOff, rayCount, rgba, (const float*)pos, out);
}

// Round 10
// 114.235 us; speedup vs baseline: 2.5625x; 1.0466x over previous
//
#include <hip/hip_runtime.h>
#include <stdint.h>

#define NRAYS 2048
#define SMAX  192
#define RESG  128
#define STEPF 0.027f
#define ERTF  1e-4f
#define CAP   (NRAYS * SMAX)   // 393216

typedef __attribute__((ext_vector_type(8)))  short bf16x8;   // 8 bf16 = 4 VGPR
typedef __attribute__((ext_vector_type(16))) float f32x16;   // MFMA 32x32 acc

// ---- bf16 helpers (RNE) ----
__device__ __forceinline__ uint32_t f2b(float x) {
    uint32_t u = __builtin_bit_cast(uint32_t, x);
    return (u + 0x7fffu + ((u >> 16) & 1u)) >> 16;
}
__device__ __forceinline__ uint32_t bpack(float lo, float hi) {
    return f2b(lo) | (f2b(hi) << 16);
}

// ---------------- ray/aabb ----------------
__device__ __forceinline__ void ray_aabb(float ox, float oy, float oz,
                                         float dx, float dy, float dz,
                                         float& tn, float& tf) {
    float ix = 1.0f / ((fabsf(dx) < 1e-9f) ? 1e-9f : dx);
    float iy = 1.0f / ((fabsf(dy) < 1e-9f) ? 1e-9f : dy);
    float iz = 1.0f / ((fabsf(dz) < 1e-9f) ? 1e-9f : dz);
    float t0x = (-1.5f - ox) * ix, t1x = (1.5f - ox) * ix;
    float t0y = (-1.5f - oy) * iy, t1y = (1.5f - oy) * iy;
    float t0z = (-1.5f - oz) * iz, t1z = (1.5f - oz) * iz;
    float tnx = fminf(t0x, t1x), tfx = fmaxf(t0x, t1x);
    float tny = fminf(t0y, t1y), tfy = fmaxf(t0y, t1y);
    float tnz = fminf(t0z, t1z), tfz = fmaxf(t0z, t1z);
    tn = fmaxf(fmaxf(fmaxf(tnx, tny), tnz), 0.0f);
    tf = fminf(fminf(tfx, tfy), tfz);
}

// ---------------- stage 1: per-ray masks + counts, fused with weight-frag prep ----------------
// blocks 0..511: count (4 rays each). blocks 512..599: prep (old k_prep block pb = b-512).
__global__ __launch_bounds__(256) void k_count_prep(
        const float* __restrict__ ro, const float* __restrict__ rd,
        const int* __restrict__ occ,
        const float* __restrict__ W0, const float* __restrict__ W1,
        const float* __restrict__ W2,
        int* __restrict__ rayCount, unsigned long long* __restrict__ masks,
        uint32_t* __restrict__ wfrag) {
    int b = blockIdx.x;
    if (b >= NRAYS / 4) {
        // ---- weight fragment prep ----
        int pb = b - NRAYS / 4;          // 0..87
        int lane = threadIdx.x;
        if (lane >= 64) return;
        int g = pb >> 2, oc = pb & 3;
        int out = oc * 32 + (lane & 31);
        const float* W; int kbase, Klim;
        if (g < 4)       { W = W0; kbase = g * 16;        Klim = 63;  }
        else if (g < 12) { W = W1; kbase = (g - 4) * 16;  Klim = 128; }
        else             { W = W2; kbase = (g - 12) * 16; Klim = 155; }
        uint32_t d[4];
        #pragma unroll
        for (int h = 0; h < 4; ++h) {
            int k0 = kbase + ((lane >> 5) << 3) + h * 2;
            float lo = (k0     < Klim) ? W[(size_t)k0 * 128 + out]       : 0.0f;
            float hi = (k0 + 1 < Klim) ? W[(size_t)(k0 + 1) * 128 + out] : 0.0f;
            d[h] = bpack(lo, hi);
        }
        ((uint4*)wfrag)[pb * 64 + lane] = make_uint4(d[0], d[1], d[2], d[3]);
        return;
    }
    int r = b * 4 + (threadIdx.x >> 6);
    int lane = threadIdx.x & 63;
    float ox = ro[r*3+0], oy = ro[r*3+1], oz = ro[r*3+2];
    float dx = rd[r*3+0], dy = rd[r*3+1], dz = rd[r*3+2];
    float tn, tf;
    ray_aabb(ox, oy, oz, dx, dy, dz, tn, tf);
    int cnt = 0;
    #pragma unroll
    for (int c = 0; c < 3; ++c) {
        int s = c * 64 + lane;
        float t_mid = (tn + STEPF * (float)s) + 0.5f * STEPF;
        bool inside = (t_mid < tf) && (tf > tn);
        bool act = false;
        if (inside) {
            float px = ox + dx * t_mid;
            float py = oy + dy * t_mid;
            float pz = oz + dz * t_mid;
            int gx = min(max((int)((px + 1.5f) / 3.0f * 128.0f), 0), RESG - 1);
            int gy = min(max((int)((py + 1.5f) / 3.0f * 128.0f), 0), RESG - 1);
            int gz = min(max((int)((pz + 1.5f) / 3.0f * 128.0f), 0), RESG - 1);
            act = occ[(gx * RESG + gy) * RESG + gz] != 0;
        }
        unsigned long long mb = __ballot(act);
        if (lane == 0) masks[r * 3 + c] = mb;
        cnt += __popcll(mb);
    }
    if (lane == 0) rayCount[r] = cnt;
}

// ---------------- stage 2: exclusive scan of 2048 ray counts ----------------
__global__ __launch_bounds__(1024) void k_scan(
        const int* __restrict__ rayCount, int* __restrict__ rayOff,
        int* __restrict__ cnt_total) {
    __shared__ int wsum[16];
    int tid = threadIdx.x;              // 0..1023, pair (2*tid, 2*tid+1)
    int a = rayCount[2 * tid], b = rayCount[2 * tid + 1];
    int s = a + b;
    int lane = tid & 63, w = tid >> 6;
    int v = s;
    #pragma unroll
    for (int off = 1; off < 64; off <<= 1) {
        int t = __shfl_up(v, off);
        if (lane >= off) v += t;
    }
    if (lane == 63) wsum[w] = v;
    __syncthreads();
    if (tid < 16) {
        int x = wsum[tid];
        #pragma unroll
        for (int off = 1; off < 16; off <<= 1) {
            int t = __shfl_up(x, off, 16);
            if (tid >= off) x += t;
        }
        wsum[tid] = x;                  // inclusive wave-sum scan
    }
    __syncthreads();
    int wbase = (w == 0) ? 0 : wsum[w - 1];
    int incl = wbase + v;
    int excl = incl - s;
    rayOff[2 * tid]     = excl;
    rayOff[2 * tid + 1] = excl + a;
    if (tid == 1023) cnt_total[0] = incl;
}

// ---------------- stage 3: write compacted ids/pos (ray-sorted, deterministic) ----------------
__global__ __launch_bounds__(256) void k_fill(
        const float* __restrict__ ro, const float* __restrict__ rd,
        const int* __restrict__ rayOff, const unsigned long long* __restrict__ masks,
        int* __restrict__ rayid, float4* __restrict__ pos) {
    int r = blockIdx.x * 4 + (threadIdx.x >> 6);
    int lane = threadIdx.x & 63;
    float ox = ro[r*3+0], oy = ro[r*3+1], oz = ro[r*3+2];
    float dx = rd[r*3+0], dy = rd[r*3+1], dz = rd[r*3+2];
    float tn, tf;
    ray_aabb(ox, oy, oz, dx, dy, dz, tn, tf);
    int base = rayOff[r];
    #pragma unroll
    for (int c = 0; c < 3; ++c) {
        unsigned long long m = masks[r * 3 + c];
        if ((m >> lane) & 1ull) {
            int within = __popcll(m & ((1ull << lane) - 1ull));
            int s = c * 64 + lane;
            float t_mid = (tn + STEPF * (float)s) + 0.5f * STEPF;
            float px = ox + dx * t_mid;
            float py = oy + dy * t_mid;
            float pz = oz + dz * t_mid;
            rayid[base + within] = r;
            pos[base + within] = make_float4(px, py, pz, t_mid);
        }
        base += __popcll(m);
    }
}

// ---------------- kernel 2: MFMA MLP, 128-sample tiles ----------------
// 8 waves = 4 out-chunks(32) x 2 sample-halves(64); each wave: 2 col-chunks of 32 samples.
// LDS ~101KB -> 1 block/CU; 44 MFMA per wave per tile (2x the old per-barrier work).
__global__ __launch_bounds__(512) void k_mlp(
        const uint32_t* __restrict__ wfrag, const float* __restrict__ wsig,
        const float* __restrict__ wrgb, const float* __restrict__ vd,
        const int* __restrict__ cnt, const int* __restrict__ rayid,
        const float4* __restrict__ pos, float4* __restrict__ rgba) {
    __shared__ __align__(16) short actA[128 * 128];   // 32KB, rowB=256B
    __shared__ __align__(16) short bufB[128 * 256];   // 64KB, rowB=512B
    __shared__ float4 sPos[128];
    __shared__ int    sRay[128];
    __shared__ float  sV[128];
    __shared__ float  sR[384];

    const int tid  = threadIdx.x;
    const int wave = tid >> 6;
    const int lane = tid & 63;
    const int oc   = wave & 3;
    const int sc   = wave >> 2;
    const int lo5  = lane & 31;
    const int hi5  = lane >> 5;

    if (tid < 128) sV[tid] = wsig[tid];
    if (tid >= 128 && tid < 512) sR[tid - 128] = wrgb[tid - 128];

    bf16x8 wf[22];
    {
        const uint4* src = (const uint4*)wfrag;
        #pragma unroll
        for (int g = 0; g < 22; ++g) {
            uint4 v = src[(g * 4 + oc) * 64 + lane];
            wf[g] = __builtin_bit_cast(bf16x8, v);
        }
    }

    const int total  = *cnt;
    const int ntiles = (total + 127) >> 7;
    const int mrow   = sc * 64 + lo5;            // cc=0 row; cc=1 row = mrow+32
    const int rswz   = (mrow & 15) << 4;         // (mrow+32)&15 == mrow&15

    for (int t = blockIdx.x; t < ntiles; t += gridDim.x) {
        const int base = t << 7;
        __syncthreads();
        if (tid < 128) {
            int gi = base + tid;
            if (gi < total) { sRay[tid] = rayid[gi]; sPos[tid] = pos[gi]; }
            else            { sRay[tid] = 0; sPos[tid] = make_float4(0.f,0.f,0.f,0.f); }
        }
        __syncthreads();

        // ---- PE: 4 threads/sample. pe_p cols 0..63 -> actA; pe_d cols 0..31 -> bufB(+256B) ----
        {
            int m = tid >> 2, p = tid & 3;
            float4 P = sPos[m];
            int swz = (m & 15) << 4;
            #pragma unroll
            for (int half = 0; half < 2; ++half) {
                uint32_t dw[4];
                #pragma unroll
                for (int jp = 0; jp < 4; ++jp) {
                    float v[2];
                    #pragma unroll
                    for (int q = 0; q < 2; ++q) {
                        int c = p * 16 + half * 8 + jp * 2 + q;
                        float val;
                        if (c < 3)        val = (c == 0) ? P.x : ((c == 1) ? P.y : P.z);
                        else if (c >= 63) val = 0.0f;
                        else {
                            int cc = c - 3, l = cc / 6, jj = cc - 6 * l;
                            int a3 = (jj >= 3) ? jj - 3 : jj;
                            float comp = (a3 == 0) ? P.x : ((a3 == 1) ? P.y : P.z);
                            float arg = comp * (float)(1 << l);
                            val = (jj < 3) ? __sinf(arg) : __cosf(arg);
                        }
                        v[q] = val;
                    }
                    dw[jp] = bpack(v[0], v[1]);
                }
                *(uint4*)((char*)actA + m * 256 + ((p * 32 + half * 16) ^ swz)) = make_uint4(dw[0], dw[1], dw[2], dw[3]);
            }
            {
                int ray = sRay[m];
                float Dx = vd[ray*3+0], Dy = vd[ray*3+1], Dz = vd[ray*3+2];
                uint32_t dw[4];
                #pragma unroll
                for (int jp = 0; jp < 4; ++jp) {
                    float v[2];
                    #pragma unroll
                    for (int q = 0; q < 2; ++q) {
                        int c = p * 8 + jp * 2 + q;     // 0..31
                        float val;
                        if (c < 3)        val = (c == 0) ? Dx : ((c == 1) ? Dy : Dz);
                        else if (c >= 27) val = 0.0f;
                        else {
                            int cc = c - 3, l = cc / 6, jj = cc - 6 * l;
                            int a3 = (jj >= 3) ? jj - 3 : jj;
                            float comp = (a3 == 0) ? Dx : ((a3 == 1) ? Dy : Dz);
                            float arg = comp * (float)(1 << l);
                            val = (jj < 3) ? __sinf(arg) : __cosf(arg);
                        }
                        v[q] = val;
                    }
                    dw[jp] = bpack(v[0], v[1]);
                }
                *(uint4*)((char*)bufB + m * 512 + ((256 + p * 16) ^ swz)) = make_uint4(dw[0], dw[1], dw[2], dw[3]);
            }
        }
        __syncthreads();

        // ---- L0: h_a = relu(pe_p @ W0) -> bufB cols 0..127 ----
        {
            f32x16 a0 = {}, a1 = {};
            #pragma unroll
            for (int kb = 0; kb < 4; ++kb) {
                int cb = (kb * 32 + (hi5 << 4)) ^ rswz;
                bf16x8 b0 = *(const bf16x8*)((const char*)actA + mrow * 256 + cb);
                bf16x8 b1 = *(const bf16x8*)((const char*)actA + (mrow + 32) * 256 + cb);
                a0 = __builtin_amdgcn_mfma_f32_32x32x16_bf16(wf[kb], b0, a0, 0, 0, 0);
                a1 = __builtin_amdgcn_mfma_f32_32x32x16_bf16(wf[kb], b1, a1, 0, 0, 0);
            }
            #pragma unroll
            for (int g = 0; g < 4; ++g) {
                int outb = (oc * 32 + g * 8 + (hi5 << 2)) * 2;
                *(uint2*)((char*)bufB + mrow * 512 + (outb ^ rswz)) =
                    make_uint2(bpack(fmaxf(a0[g*4+0],0.f), fmaxf(a0[g*4+1],0.f)),
                               bpack(fmaxf(a0[g*4+2],0.f), fmaxf(a0[g*4+3],0.f)));
                *(uint2*)((char*)bufB + (mrow + 32) * 512 + (outb ^ rswz)) =
                    make_uint2(bpack(fmaxf(a1[g*4+0],0.f), fmaxf(a1[g*4+1],0.f)),
                               bpack(fmaxf(a1[g*4+2],0.f), fmaxf(a1[g*4+3],0.f)));
            }
        }
        __syncthreads();

        // ---- L1: h_b = relu(h_a @ W1) -> actA ----
        {
            f32x16 a0 = {}, a1 = {};
            #pragma unroll
            for (int kb = 0; kb < 8; ++kb) {
                int cb = (kb * 32 + (hi5 << 4)) ^ rswz;
                bf16x8 b0 = *(const bf16x8*)((const char*)bufB + mrow * 512 + cb);
                bf16x8 b1 = *(const bf16x8*)((const char*)bufB + (mrow + 32) * 512 + cb);
                a0 = __builtin_amdgcn_mfma_f32_32x32x16_bf16(wf[4 + kb], b0, a0, 0, 0, 0);
                a1 = __builtin_amdgcn_mfma_f32_32x32x16_bf16(wf[4 + kb], b1, a1, 0, 0, 0);
            }
            #pragma unroll
            for (int g = 0; g < 4; ++g) {
                int outb = (oc * 32 + g * 8 + (hi5 << 2)) * 2;
                *(uint2*)((char*)actA + mrow * 256 + (outb ^ rswz)) =
                    make_uint2(bpack(fmaxf(a0[g*4+0],0.f), fmaxf(a0[g*4+1],0.f)),
                               bpack(fmaxf(a0[g*4+2],0.f), fmaxf(a0[g*4+3],0.f)));
                *(uint2*)((char*)actA + (mrow + 32) * 256 + (outb ^ rswz)) =
                    make_uint2(bpack(fmaxf(a1[g*4+0],0.f), fmaxf(a1[g*4+1],0.f)),
                               bpack(fmaxf(a1[g*4+2],0.f), fmaxf(a1[g*4+3],0.f)));
            }
        }
        __syncthreads();

        // ---- L2: h2 = relu([h_b | pe_d] @ W2) -> bufB cols 0..127 ----
        {
            f32x16 a0 = {}, a1 = {};
            #pragma unroll
            for (int kb = 0; kb < 8; ++kb) {
                int cb = (kb * 32 + (hi5 << 4)) ^ rswz;
                bf16x8 b0 = *(const bf16x8*)((const char*)actA + mrow * 256 + cb);
                bf16x8 b1 = *(const bf16x8*)((const char*)actA + (mrow + 32) * 256 + cb);
                a0 = __builtin_amdgcn_mfma_f32_32x32x16_bf16(wf[12 + kb], b0, a0, 0, 0, 0);
                a1 = __builtin_amdgcn_mfma_f32_32x32x16_bf16(wf[12 + kb], b1, a1, 0, 0, 0);
            }
            #pragma unroll
            for (int kb = 8; kb < 10; ++kb) {
                int cb = (kb * 32 + (hi5 << 4)) ^ rswz;
                bf16x8 b0 = *(const bf16x8*)((const char*)bufB + mrow * 512 + cb);
                bf16x8 b1 = *(const bf16x8*)((const char*)bufB + (mrow + 32) * 512 + cb);
                a0 = __builtin_amdgcn_mfma_f32_32x32x16_bf16(wf[12 + kb], b0, a0, 0, 0, 0);
                a1 = __builtin_amdgcn_mfma_f32_32x32x16_bf16(wf[12 + kb], b1, a1, 0, 0, 0);
            }
            #pragma unroll
            for (int g = 0; g < 4; ++g) {
                int outb = (oc * 32 + g * 8 + (hi5 << 2)) * 2;
                *(uint2*)((char*)bufB + mrow * 512 + (outb ^ rswz)) =
                    make_uint2(bpack(fmaxf(a0[g*4+0],0.f), fmaxf(a0[g*4+1],0.f)),
                               bpack(fmaxf(a0[g*4+2],0.f), fmaxf(a0[g*4+3],0.f)));
                *(uint2*)((char*)bufB + (mrow + 32) * 512 + (outb ^ rswz)) =
                    make_uint2(bpack(fmaxf(a1[g*4+0],0.f), fmaxf(a1[g*4+1],0.f)),
                               bpack(fmaxf(a1[g*4+2],0.f), fmaxf(a1[g*4+3],0.f)));
            }
        }
        __syncthreads();

        // ---- heads: sigma = h_b @ wsig ; rgb = sigmoid(h2 @ wrgb). 4 threads/sample ----
        {
            int m = tid >> 2, p = tid & 3;
            int swz = (m & 15) << 4;
            float sp = 0.f, r0 = 0.f, r1 = 0.f, r2 = 0.f;
            #pragma unroll
            for (int hh = 0; hh < 4; ++hh) {
                uint4 q = *(const uint4*)((const char*)actA + m * 256 + ((p * 64 + hh * 16) ^ swz));
                uint32_t w[4] = {q.x, q.y, q.z, q.w};
                #pragma unroll
                for (int e = 0; e < 4; ++e) {
                    int j = p * 32 + hh * 8 + e * 2;
                    float a0 = __builtin_bit_cast(float, w[e] << 16);
                    float a1 = __builtin_bit_cast(float, w[e] & 0xffff0000u);
                    sp = fmaf(a0, sV[j], sp);
                    sp = fmaf(a1, sV[j + 1], sp);
                }
            }
            #pragma unroll
            for (int hh = 0; hh < 4; ++hh) {
                uint4 q = *(const uint4*)((const char*)bufB + m * 512 + ((p * 64 + hh * 16) ^ swz));
                uint32_t w[4] = {q.x, q.y, q.z, q.w};
                #pragma unroll
                for (int e = 0; e < 4; ++e) {
                    int j = p * 32 + hh * 8 + e * 2;
                    float a0 = __builtin_bit_cast(float, w[e] << 16);
                    float a1 = __builtin_bit_cast(float, w[e] & 0xffff0000u);
                    r0 = fmaf(a0, sR[j*3+0], r0); r1 = fmaf(a0, sR[j*3+1], r1); r2 = fmaf(a0, sR[j*3+2], r2);
                    r0 = fmaf(a1, sR[(j+1)*3+0], r0); r1 = fmaf(a1, sR[(j+1)*3+1], r1); r2 = fmaf(a1, sR[(j+1)*3+2], r2);
                }
            }
            #pragma unroll
            for (int off = 1; off < 4; off <<= 1) {
                sp += __shfl_xor(sp, off);
                r0 += __shfl_xor(r0, off);
                r1 += __shfl_xor(r1, off);
                r2 += __shfl_xor(r2, off);
            }
            if (p == 0 && (base + m) < total) {
                float alpha = 1.0f - __expf(-fmaxf(sp, 0.0f) * STEPF);
                float c0 = 1.0f / (1.0f + __expf(-r0));
                float c1 = 1.0f / (1.0f + __expf(-r1));
                float c2 = 1.0f / (1.0f + __expf(-r2));
                rgba[base + m] = make_float4(c0, c1, c2, alpha);
            }
        }
    }
}

// ---------------- kernel 3: compositing over compact per-ray ranges ----------------
__global__ __launch_bounds__(256) void k_render(
        const int* __restrict__ rayOff, const int* __restrict__ rayCount,
        const float4* __restrict__ rgba, const float* __restrict__ posw,
        float* __restrict__ out) {
    int r = blockIdx.x * 4 + (threadIdx.x >> 6);
    int lane = threadIdx.x & 63;
    int off = rayOff[r], cnt = rayCount[r];
    float T_run = 1.0f;
    float cr = 0.f, cg = 0.f, cb = 0.f, opa = 0.f, dep = 0.f;
    for (int j = 0; j < cnt; j += 64) {
        int idx = j + lane;
        float4 f = make_float4(0.f, 0.f, 0.f, 0.f);
        float tmid = 0.f;
        if (idx < cnt) {
            f = rgba[off + idx];
            tmid = posw[(size_t)(off + idx) * 4 + 3];
        }
        float p = (1.0f - f.w) + 1e-10f;
        #pragma unroll
        for (int o = 1; o < 64; o <<= 1) {
            float v = __shfl_up(p, o);
            if (lane >= o) p *= v;
        }
        float pprev = __shfl_up(p, 1);
        float Texc = (lane == 0) ? T_run : T_run * pprev;
        Texc = (Texc > ERTF) ? Texc : 0.0f;
        float w = Texc * f.w;
        cr += w * f.x; cg += w * f.y; cb += w * f.z;
        opa += w; dep += w * tmid;
        T_run *= __shfl(p, 63);
        if (T_run <= ERTF) break;      // exact: all later exclusive-T <= ERT -> zero weight
    }
    #pragma unroll
    for (int o = 32; o; o >>= 1) {
        cr  += __shfl_xor(cr, o);
        cg  += __shfl_xor(cg, o);
        cb  += __shfl_xor(cb, o);
        opa += __shfl_xor(opa, o);
        dep += __shfl_xor(dep, o);
    }
    if (lane == 0) {
        out[r * 3 + 0] = cr + (1.0f - opa);
        out[r * 3 + 1] = cg + (1.0f - opa);
        out[r * 3 + 2] = cb + (1.0f - opa);
        out[NRAYS * 3 + r] = dep;            // depth
        out[NRAYS * 4 + r] = opa;            // opacity
    }
}

extern "C" void kernel_launch(void* const* d_in, const int* in_sizes, int n_in,
                              void* d_out, int out_size, void* d_ws, size_t ws_size,
                              hipStream_t stream) {
    const float* ro   = (const float*)d_in[0];
    const float* rd   = (const float*)d_in[1];
    const int*   occ  = (const int*)d_in[2];
    const float* W0   = (const float*)d_in[3];
    const float* W1   = (const float*)d_in[4];
    const float* wsig = (const float*)d_in[5];
    const float* W2   = (const float*)d_in[6];
    const float* wrgb = (const float*)d_in[7];
    float* out = (float*)d_out;

    char* ws = (char*)d_ws;
    int*                cnt_total = (int*)ws;                              // 16 B
    int*                rayCount  = (int*)(ws + 16);                       // 8 KB
    int*                rayOff    = (int*)(ws + 8208);                     // 8 KB
    unsigned long long* masks     = (unsigned long long*)(ws + 16400);     // 48 KB
    int*                rayid     = (int*)(ws + 65552);                    // CAP*4
    float4*             pos       = (float4*)(ws + 65552 + (size_t)CAP * 8);
    float4*             rgba      = (float4*)(ws + 65552 + (size_t)CAP * 24);
    uint32_t*           wfrag     = (uint32_t*)(ws + 65552 + (size_t)CAP * 40);  // 88*64*16B

    k_count_prep <<<NRAYS / 4 + 88, 256, 0, stream>>>(ro, rd, occ, W0, W1, W2,
                                                      rayCount, masks, wfrag);
    k_scan  <<<1, 1024, 0, stream>>>(rayCount, rayOff, cnt_total);
    k_fill  <<<NRAYS / 4, 256, 0, stream>>>(ro, rd, rayOff, masks, rayid, pos);
    k_mlp   <<<256, 512, 0, stream>>>(wfrag, wsig, wrgb, rd, cnt_total, rayid, pos, rgba);
    k_render<<<NRAYS / 4, 256, 0, stream>>>(rayOff, rayCount, rgba, (const float*)pos, out);
}